// Round 9
// baseline (304.349 us; speedup 1.0000x reference)
//
#include <hip/hip_runtime.h>

#define DIM 128
#define PAD 64

typedef __bf16 bf16x8 __attribute__((ext_vector_type(8)));
typedef float f32x4 __attribute__((ext_vector_type(4)));
typedef unsigned short ushort8 __attribute__((ext_vector_type(8)));

__device__ __forceinline__ unsigned short f2bf(float f) {
    union { float f; unsigned u; } x; x.f = f;
    unsigned r = x.u + 0x7FFF + ((x.u >> 16) & 1);   // RNE
    return (unsigned short)(r >> 16);
}

__device__ __forceinline__ float bf2f(unsigned short u) {
    union { unsigned u; float f; } x; x.u = ((unsigned)u) << 16;
    return x.f;
}

// ---------- fused build: edge scatter (atomic-latency-bound) + conv/pack (streaming,
// hides in the atomic shadow). counts pre-zeroed via hipMemsetAsync.
// NOTE: nontemporal store REQUIRED for correctness (R12): normal 4B stores to one 64B
// col_pad line from blocks on different XCDs -> partially-dirty non-coherent L2 copies
// -> writeback clobbers other XCDs' bytes. nt bypasses L2 -> byte-granular HBM writes.
// R3 post-mortem: atomicExch did NOT reduce WRITE_SIZE and was +16us slower.
__global__ void build_fused(const int* __restrict__ src, const int* __restrict__ dst,
                            int* __restrict__ counts, int* __restrict__ col_pad,
                            const float* __restrict__ x, unsigned short* __restrict__ xb,
                            const float* __restrict__ W_self, const float* __restrict__ W_neigh,
                            unsigned short* __restrict__ Bp, int E, int n8) {
    int t = blockIdx.x * blockDim.x + threadIdx.x;
    if (t < E) {
        int v = dst[t];
        int pos = atomicAdd(&counts[v], 1);
        if (pos < PAD)
            __builtin_nontemporal_store(src[t], &col_pad[(size_t)v * PAD + pos]);
    }
    if (t < n8) {
        const float4* p = (const float4*)(x + (size_t)t * 8);
        float4 a = p[0], b = p[1];
        ushort8 o = {f2bf(a.x), f2bf(a.y), f2bf(a.z), f2bf(a.w),
                     f2bf(b.x), f2bf(b.y), f2bf(b.z), f2bf(b.w)};
        *(ushort8*)(xb + (size_t)t * 8) = o;
    } else if (t < n8 + 3 * 64 * 64) {
        int u = t - n8;
        int lane = u & 63;
        int g = u >> 6;
        int l = g >> 6;
        int r = g & 63;
        int ns = r >> 3, ks = r & 7;
        const float* Wsl = W_self + (size_t)l * DIM * DIM;
        const float* Wnl = W_neigh + (size_t)l * DIM * DIM;
        unsigned short* dstp = Bp + (size_t)l * 32768 + ((size_t)(ns * 8 + ks) * 64 + lane) * 8;
        int nn = ns * 16 + (lane & 15);
        int kbase = ks * 32 + (lane >> 4) * 8;
        ushort8 o;
        #pragma unroll
        for (int j = 0; j < 8; ++j) {
            int k = kbase + j;
            float v = (k < 128) ? Wsl[(size_t)k * DIM + nn] : Wnl[(size_t)(k - 128) * DIM + nn];
            o[j] = f2bf(v);
        }
        *(ushort8*)dstp = o;
    }
}

// ---------- gather v6: feature-chunk partitioned, XCD-pinned.
// R7 post-mortem: idx-staging null; with R5/R3 nulls the gather is bound by
// outstanding-line capacity x latency (~4KB in flight/CU at LLC ~250ns). Lever:
// cut the latency. FETCH=81MB vs 12.8MB working set shows each XCD's 4MB L2
// refetches nearly all of h. Split DIM into 4 chunks of 64B; chunk = bid&3 with
// round-robin bid%8->XCD [T1/m09] pins chunk c to XCDs {c, c+4} -> per-XCD set
// 3.2MB, L2-resident -> ~200cy instead of ~600cy per line, ~3x BW/CU under the
// capacity model. Mapping miss = perf-only. Compact idx staging (cc slots, not
// PAD) cuts idx fetch 12.8->3.2 MB/layer. Each node handled by 16 lanes = 4
// units x 4 lanes; unit reads one neighbor's 64B chunk; 2 units-deep unroll.
__global__ __launch_bounds__(256, 6) void agg_k(
    const unsigned short* __restrict__ hb, const int* __restrict__ counts,
    const int* __restrict__ col_pad, unsigned short* __restrict__ aggb, int n)
{
    __shared__ int ldsIdx[16 * PAD];               // 4 KB

    const int bid   = blockIdx.x;
    const int chunk = bid & 3;                     // 32 elems = 64 B
    const int tile  = bid >> 2;
    const int nb0   = tile * 16;

    const int tid = threadIdx.x;
    const int j   = tid >> 4;                      // node slot 0..15
    const int t   = tid & 15;
    const int u   = t >> 2;                        // unit 0..3
    const int p   = t & 3;                         // 16B slice within 64B chunk

    const int node = nb0 + j;
    const int c    = (node < n) ? counts[node] : 0;
    const int cc   = min(c, PAD);

    // compact idx stage: only used slots; 16 consecutive slots per round, coalesced
    {
        const int* cpg = col_pad + (size_t)node * PAD;
        for (int s = t; s < cc; s += 16)
            ldsIdx[j * PAD + s] = cpg[s];
    }
    __syncthreads();

    const int* cp = &ldsIdx[j * PAD];
    const unsigned short* hbase = hb + chunk * 32 + p * 8;

    float a[8] = {0.f, 0.f, 0.f, 0.f, 0.f, 0.f, 0.f, 0.f};
    for (int i = 0; i < cc; i += 8) {              // 2 neighbors per unit per iter
        const int i0 = i + u, i1 = i + 4 + u;
        const int u0 = (i0 < cc) ? cp[i0] : cp[i]; // cp[i] staged since i < cc
        const int u1 = (i1 < cc) ? cp[i1] : cp[i];
        const float m0 = (i0 < cc) ? 1.f : 0.f;
        const float m1 = (i1 < cc) ? 1.f : 0.f;
        ushort8 v0 = *(const ushort8*)(hbase + (size_t)u0 * DIM);
        ushort8 v1 = *(const ushort8*)(hbase + (size_t)u1 * DIM);
        #pragma unroll
        for (int q = 0; q < 8; ++q)
            a[q] += m0 * bf2f(v0[q]) + m1 * bf2f(v1[q]);
    }
    // reduce across the 4 units (lanes stride 4, 8 within the node's 16 lanes)
    #pragma unroll
    for (int q = 0; q < 8; ++q) {
        a[q] += __shfl_xor(a[q], 4, 64);
        a[q] += __shfl_xor(a[q], 8, 64);
    }
    if (u == 0 && node < n) {
        const float s = 1.0f / (float)(c > 0 ? c : 1);
        ushort8 o = {f2bf(a[0] * s), f2bf(a[1] * s), f2bf(a[2] * s), f2bf(a[3] * s),
                     f2bf(a[4] * s), f2bf(a[5] * s), f2bf(a[6] * s), f2bf(a[7] * s)};
        *(ushort8*)(aggb + (size_t)node * DIM + chunk * 32 + p * 8) = o;   // 4x16B/node
    }
}

// ---------- GEMM v6: R0's verified fragment layout, LDS-free (B straight from
// global, L2-resident; A-self from hb, A-neigh from aggb). 782 blocks, high
// occupancy, no barriers. ----------
__global__ __launch_bounds__(256, 4) void gemm_k(
    const unsigned short* __restrict__ hb, const unsigned short* __restrict__ aggb,
    const unsigned short* __restrict__ Bp, const float* __restrict__ bias,
    unsigned short* __restrict__ out_bf, float* __restrict__ out_f32,
    int n, int do_relu)
{
    const int tid  = threadIdx.x;
    const int w    = tid >> 6;
    const int lane = tid & 63;
    const int m    = lane & 15;
    const int quad = lane >> 4;

    const int row0 = blockIdx.x * 64 + w * 16;
    int ar = row0 + m;
    if (ar >= n) ar = n - 1;           // clamp; invalid rows never stored
    const unsigned short* hp = hb + (size_t)ar * DIM + quad * 8;
    const unsigned short* ap = aggb + (size_t)ar * DIM + quad * 8;

    f32x4 acc[8];
    #pragma unroll
    for (int ns = 0; ns < 8; ++ns) acc[ns] = (f32x4){0.f, 0.f, 0.f, 0.f};

    #pragma unroll
    for (int ks = 0; ks < 8; ++ks) {
        bf16x8 a = (ks < 4) ? *(const bf16x8*)(hp + ks * 32)
                            : *(const bf16x8*)(ap + (ks - 4) * 32);
        #pragma unroll
        for (int ns = 0; ns < 8; ++ns) {
            bf16x8 b = *(const bf16x8*)(Bp + ((size_t)(ns * 8 + ks) * 64 + lane) * 8);
            acc[ns] = __builtin_amdgcn_mfma_f32_16x16x32_bf16(a, b, acc[ns], 0, 0, 0);
        }
    }

    #pragma unroll
    for (int ns = 0; ns < 8; ++ns) {
        int col = ns * 16 + m;
        float bb = bias[col];
        #pragma unroll
        for (int r = 0; r < 4; ++r) {
            int gr = row0 + quad * 4 + r;
            if (gr < n) {
                float v = acc[ns][r] + bb;
                if (do_relu) v = fmaxf(v, 0.f);
                if (out_bf) out_bf[(size_t)gr * DIM + col] = f2bf(v);
                else        out_f32[(size_t)gr * DIM + col] = v;
            }
        }
    }
}

// ---------- launch ----------

extern "C" void kernel_launch(void* const* d_in, const int* in_sizes, int n_in,
                              void* d_out, int out_size, void* d_ws, size_t ws_size,
                              hipStream_t stream) {
    const float* x      = (const float*)d_in[0];
    const int*   src    = (const int*)d_in[1];
    const int*   dst    = (const int*)d_in[2];
    const float* W_self = (const float*)d_in[3];
    const float* W_neigh= (const float*)d_in[4];
    const float* bias   = (const float*)d_in[5];
    float* out = (float*)d_out;

    const int n = in_sizes[0] / DIM;   // 50000
    const int e = in_sizes[1];         // 800000

    char* ws = (char*)d_ws;
    size_t off = 0;
    auto alloc = [&](size_t bytes) -> void* {
        void* p = ws + off;
        off += (bytes + 255) & ~(size_t)255;
        return p;
    };
    int*   counts  = (int*)alloc((size_t)n * 4);
    int*   col_pad = (int*)alloc((size_t)n * PAD * 4);
    unsigned short* x_bf  = (unsigned short*)alloc((size_t)n * DIM * 2);
    unsigned short* h_a   = (unsigned short*)alloc((size_t)n * DIM * 2);
    unsigned short* h_b   = (unsigned short*)alloc((size_t)n * DIM * 2);
    unsigned short* aggb  = (unsigned short*)alloc((size_t)n * DIM * 2);
    unsigned short* Bp    = (unsigned short*)alloc((size_t)3 * 32768 * 2);

    const int n8 = n * DIM / 8;         // 800000

    hipMemsetAsync(counts, 0, (size_t)n * 4, stream);
    const int build_units = (e > n8 + 3 * 64 * 64) ? e : (n8 + 3 * 64 * 64);
    build_fused<<<(build_units + 255) / 256, 256, 0, stream>>>(
        src, dst, counts, col_pad, x, x_bf, W_self, W_neigh, Bp, e, n8);

    const int agg_grid  = ((n + 15) / 16) * 4;   // 3125 tiles x 4 chunks = 12500
    const int gemm_grid = (n + 63) / 64;         // 782

    // layer 0
    agg_k<<<agg_grid, 256, 0, stream>>>(x_bf, counts, col_pad, aggb, n);
    gemm_k<<<gemm_grid, 256, 0, stream>>>(x_bf, aggb, Bp, bias, h_a, nullptr, n, 1);
    // layer 1
    agg_k<<<agg_grid, 256, 0, stream>>>(h_a, counts, col_pad, aggb, n);
    gemm_k<<<gemm_grid, 256, 0, stream>>>(h_a, aggb, Bp + 32768, bias + DIM, h_b, nullptr, n, 1);
    // layer 2
    agg_k<<<agg_grid, 256, 0, stream>>>(h_b, counts, col_pad, aggb, n);
    gemm_k<<<gemm_grid, 256, 0, stream>>>(h_b, aggb, Bp + 2 * 32768, bias + 2 * DIM,
                                          nullptr, out, n, 0);
}

// Round 11
// 248.629 us; speedup vs baseline: 1.2241x; 1.2241x over previous
//
#include <hip/hip_runtime.h>

#define DIM 128
#define PAD 64

typedef __bf16 bf16x8 __attribute__((ext_vector_type(8)));
typedef float f32x4 __attribute__((ext_vector_type(4)));
typedef unsigned short ushort8 __attribute__((ext_vector_type(8)));

__device__ __forceinline__ unsigned short f2bf(float f) {
    union { float f; unsigned u; } x; x.f = f;
    unsigned r = x.u + 0x7FFF + ((x.u >> 16) & 1);   // RNE
    return (unsigned short)(r >> 16);
}

__device__ __forceinline__ float bf2f(unsigned short u) {
    union { unsigned u; float f; } x; x.u = ((unsigned)u) << 16;
    return x.f;
}

// ---------- fused build: edge scatter + conv/pack.
// R9: scatter unrolled 4x (200K threads x 4 edges, int4 index loads). Build was
// 57us at VALU 1%/HBM 17%/occ 62% -> latency x parallelism bound on the
// atomicAdd->nt-store chain (1 atomic in flight per lane). 4 independent
// atomics per lane before the dependent stores ~4x the in-flight atomics/CU.
// NOTE: nontemporal store REQUIRED for correctness (R12): normal 4B stores to one 64B
// col_pad line from blocks on different XCDs -> partially-dirty non-coherent L2 copies
// -> writeback clobbers other XCDs' bytes. nt bypasses L2 -> byte-granular HBM writes.
// R3: atomicExch did NOT reduce WRITE_SIZE and was +16us slower. nt store kept.
__global__ void build_fused(const int* __restrict__ src, const int* __restrict__ dst,
                            int* __restrict__ counts, int* __restrict__ col_pad,
                            const float* __restrict__ x, unsigned short* __restrict__ xb,
                            const float* __restrict__ W_self, const float* __restrict__ W_neigh,
                            unsigned short* __restrict__ Bp, int E, int n8) {
    int t = blockIdx.x * blockDim.x + threadIdx.x;
    const int E4 = (E + 3) >> 2;
    if (t < E4) {
        const int base = t * 4;
        if (base + 3 < E) {
            int4 dv = *(const int4*)(dst + base);
            int4 sv = *(const int4*)(src + base);
            int p0 = atomicAdd(&counts[dv.x], 1);
            int p1 = atomicAdd(&counts[dv.y], 1);
            int p2 = atomicAdd(&counts[dv.z], 1);
            int p3 = atomicAdd(&counts[dv.w], 1);
            if (p0 < PAD) __builtin_nontemporal_store(sv.x, &col_pad[(size_t)dv.x * PAD + p0]);
            if (p1 < PAD) __builtin_nontemporal_store(sv.y, &col_pad[(size_t)dv.y * PAD + p1]);
            if (p2 < PAD) __builtin_nontemporal_store(sv.z, &col_pad[(size_t)dv.z * PAD + p2]);
            if (p3 < PAD) __builtin_nontemporal_store(sv.w, &col_pad[(size_t)dv.w * PAD + p3]);
        } else {
            for (int k = 0; k < 4; ++k) {
                int e = base + k;
                if (e < E) {
                    int v = dst[e];
                    int pos = atomicAdd(&counts[v], 1);
                    if (pos < PAD)
                        __builtin_nontemporal_store(src[e], &col_pad[(size_t)v * PAD + pos]);
                }
            }
        }
    }
    if (t < n8) {
        const float4* p = (const float4*)(x + (size_t)t * 8);
        float4 a = p[0], b = p[1];
        ushort8 o = {f2bf(a.x), f2bf(a.y), f2bf(a.z), f2bf(a.w),
                     f2bf(b.x), f2bf(b.y), f2bf(b.z), f2bf(b.w)};
        *(ushort8*)(xb + (size_t)t * 8) = o;
    } else if (t < n8 + 3 * 64 * 64) {
        int u = t - n8;
        int lane = u & 63;
        int g = u >> 6;
        int l = g >> 6;
        int r = g & 63;
        int ns = r >> 3, ks = r & 7;
        const float* Wsl = W_self + (size_t)l * DIM * DIM;
        const float* Wnl = W_neigh + (size_t)l * DIM * DIM;
        unsigned short* dstp = Bp + (size_t)l * 32768 + ((size_t)(ns * 8 + ks) * 64 + lane) * 8;
        int nn = ns * 16 + (lane & 15);
        int kbase = ks * 32 + (lane >> 4) * 8;
        ushort8 o;
        #pragma unroll
        for (int j = 0; j < 8; ++j) {
            int k = kbase + j;
            float v = (k < 128) ? Wsl[(size_t)k * DIM + nn] : Wnl[(size_t)(k - 128) * DIM + nn];
            o[j] = f2bf(v);
        }
        *(ushort8*)dstp = o;
    }
}

// ---------- fused layer v5 (best measured: 243.5us total): 128 thr / 16-node
// tile, 4-wide masked gather, B from global, XOR-swizzled ldsA, LDS-staged idx.
// R9 post-mortem: v6 chunked/XCD-pinned gather REGRESSED (+60us; chunked gather
// alone ~68us/layer > whole fused layer 62us; no L2-hit gain) -> reverted. ----------
__global__ __launch_bounds__(128, 6) void layer_k(
    const unsigned short* __restrict__ hb,
    const int* __restrict__ counts, const int* __restrict__ col_pad,
    const unsigned short* __restrict__ Bp, const float* __restrict__ bias,
    unsigned short* __restrict__ out_bf, float* __restrict__ out_f32,
    int n, int do_relu)
{
    __shared__ int ldsIdx[16 * PAD];               // 4096 B: block's index lists
    __shared__ int ldsCnt[16];
    __shared__ unsigned short ldsA[16 * 128];      // 4096 B: 16 x 128 bf16 agg tile

    const int tid  = threadIdx.x;
    const int w    = tid >> 6;     // 0..1
    const int lane = tid & 63;
    const int li   = lane & 15;    // 16B chunk idx (gather) / output row-in-16 (gemm)
    const int grp  = lane >> 4;    // node slot (gather) / k-quad (gemm)
    const int g    = w * 4 + grp;  // gather group id 0..7

    const int nb0 = blockIdx.x * 16;

    // ---- stage idx lists: 16 nodes x 64 ints = 4KB, contiguous in col_pad ----
    {
        const int4* s = (const int4*)(col_pad + (size_t)nb0 * PAD);
        int4* d = (int4*)ldsIdx;
        d[tid]       = s[tid];
        d[tid + 128] = s[tid + 128];
    }
    if (tid < 16) {
        const int node = nb0 + tid;
        ldsCnt[tid] = (node < n) ? counts[node] : 0;
    }
    __syncthreads();

    // ---- gather: each 16-lane group aggregates one node per round, 2 rounds ----
    #pragma unroll
    for (int r = 0; r < 2; ++r) {
        const int row = r * 8 + g;                 // 0..15 local row
        const int c   = ldsCnt[row];
        const int cc  = min(c, PAD);
        const int* cp = &ldsIdx[row * PAD];        // LDS; group-uniform -> broadcast
        float a[8] = {0.f, 0.f, 0.f, 0.f, 0.f, 0.f, 0.f, 0.f};
        for (int i = 0; i < cc; i += 4) {
            int4 uu = *(const int4*)(cp + i);
            const int rem = cc - i;                // >= 1
            const float m1 = rem > 1 ? 1.f : 0.f;
            const float m2 = rem > 2 ? 1.f : 0.f;
            const float m3 = rem > 3 ? 1.f : 0.f;
            const int u1 = rem > 1 ? uu.y : uu.x;  // clamp addr to a valid index
            const int u2 = rem > 2 ? uu.z : uu.x;
            const int u3 = rem > 3 ? uu.w : uu.x;
            ushort8 v0 = *(const ushort8*)(hb + (size_t)uu.x * DIM + li * 8);
            ushort8 v1 = *(const ushort8*)(hb + (size_t)u1   * DIM + li * 8);
            ushort8 v2 = *(const ushort8*)(hb + (size_t)u2   * DIM + li * 8);
            ushort8 v3 = *(const ushort8*)(hb + (size_t)u3   * DIM + li * 8);
            #pragma unroll
            for (int j = 0; j < 8; ++j)
                a[j] += (bf2f(v0[j]) + m1 * bf2f(v1[j])) +
                        (m2 * bf2f(v2[j]) + m3 * bf2f(v3[j]));
        }
        const float s = 1.0f / (float)(c > 0 ? c : 1);
        ushort8 o = {f2bf(a[0] * s), f2bf(a[1] * s), f2bf(a[2] * s), f2bf(a[3] * s),
                     f2bf(a[4] * s), f2bf(a[5] * s), f2bf(a[6] * s), f2bf(a[7] * s)};
        // swizzled store: logical chunk li of row -> slot li ^ (row&7)  (G4/T2)
        *(ushort8*)&ldsA[((size_t)row * 16 + (li ^ (row & 7))) * 8] = o;
    }
    __syncthreads();

    // ---- GEMM: wave w -> 16 rows x 64 cols (ns half w). B frags straight from
    // global (L2-resident, coalesced 1KB per frag per wave). ----
    const int nsb  = w * 4;
    const int row0 = nb0;
    int ar = row0 + li;
    if (ar >= n) ar = n - 1;                       // clamp; invalid rows never stored
    const unsigned short* hp = hb + (size_t)ar * DIM + grp * 8;
    const int arow = li;
    const int sw = arow & 7;

    f32x4 acc[4];
    #pragma unroll
    for (int nsi = 0; nsi < 4; ++nsi) acc[nsi] = (f32x4){0.f, 0.f, 0.f, 0.f};

    #pragma unroll
    for (int ks = 0; ks < 8; ++ks) {
        bf16x8 av;
        if (ks < 4) {
            av = *(const bf16x8*)(hp + ks * 32);
        } else {
            int ch = ((ks - 4) * 4 + grp) ^ sw;    // inverse of the gather swizzle
            av = *(const bf16x8*)&ldsA[((size_t)arow * 16 + ch) * 8];
        }
        #pragma unroll
        for (int nsi = 0; nsi < 4; ++nsi) {
            const int ns = nsb + nsi;
            bf16x8 b = *(const bf16x8*)(Bp + ((size_t)(ns * 8 + ks) * 64 + lane) * 8);
            acc[nsi] = __builtin_amdgcn_mfma_f32_16x16x32_bf16(av, b, acc[nsi], 0, 0, 0);
        }
    }

    #pragma unroll
    for (int nsi = 0; nsi < 4; ++nsi) {
        int col = (nsb + nsi) * 16 + li;
        float bb = bias[col];
        #pragma unroll
        for (int r = 0; r < 4; ++r) {
            int gr = row0 + grp * 4 + r;
            if (gr < n) {
                float v = acc[nsi][r] + bb;
                if (do_relu) v = fmaxf(v, 0.f);
                if (out_bf) out_bf[(size_t)gr * DIM + col] = f2bf(v);
                else        out_f32[(size_t)gr * DIM + col] = v;
            }
        }
    }
}

// ---------- launch ----------

extern "C" void kernel_launch(void* const* d_in, const int* in_sizes, int n_in,
                              void* d_out, int out_size, void* d_ws, size_t ws_size,
                              hipStream_t stream) {
    const float* x      = (const float*)d_in[0];
    const int*   src    = (const int*)d_in[1];
    const int*   dst    = (const int*)d_in[2];
    const float* W_self = (const float*)d_in[3];
    const float* W_neigh= (const float*)d_in[4];
    const float* bias   = (const float*)d_in[5];
    float* out = (float*)d_out;

    const int n = in_sizes[0] / DIM;   // 50000
    const int e = in_sizes[1];         // 800000

    char* ws = (char*)d_ws;
    size_t off = 0;
    auto alloc = [&](size_t bytes) -> void* {
        void* p = ws + off;
        off += (bytes + 255) & ~(size_t)255;
        return p;
    };
    int*   counts  = (int*)alloc((size_t)n * 4);
    int*   col_pad = (int*)alloc((size_t)n * PAD * 4);
    unsigned short* x_bf  = (unsigned short*)alloc((size_t)n * DIM * 2);
    unsigned short* h_a   = (unsigned short*)alloc((size_t)n * DIM * 2);
    unsigned short* h_b   = (unsigned short*)alloc((size_t)n * DIM * 2);
    unsigned short* Bp    = (unsigned short*)alloc((size_t)3 * 32768 * 2);

    const int n8 = n * DIM / 8;         // 800000

    hipMemsetAsync(counts, 0, (size_t)n * 4, stream);
    const int build_units = n8 + 3 * 64 * 64;   // 812288 >= (e+3)/4 scatter threads
    build_fused<<<(build_units + 255) / 256, 256, 0, stream>>>(
        src, dst, counts, col_pad, x, x_bf, W_self, W_neigh, Bp, e, n8);

    const int layer_grid = (n + 15) / 16;   // 3125

    layer_k<<<layer_grid, 128, 0, stream>>>(x_bf, counts, col_pad, Bp, bias,
                                            h_a, nullptr, n, 1);
    layer_k<<<layer_grid, 128, 0, stream>>>(h_a, counts, col_pad, Bp + 32768, bias + DIM,
                                            h_b, nullptr, n, 1);
    layer_k<<<layer_grid, 128, 0, stream>>>(h_b, counts, col_pad, Bp + 2 * 32768, bias + 2 * DIM,
                                            nullptr, out, n, 0);
}